// Round 1
// baseline (4264.240 us; speedup 1.0000x reference)
//
#include <hip/hip_runtime.h>
#include <hip/hip_bf16.h>

#define MFMA_BF16 __builtin_amdgcn_mfma_f32_16x16x32_bf16

typedef __attribute__((ext_vector_type(8))) short short8;
typedef __attribute__((ext_vector_type(4))) float f32x4;

#define NB 16384
#define NH 15
#define NS 32
#define ND 256
#define NHID 256
#define NA 6

// bf16 weight workspace layout (element offsets)
#define OFF_A0   0         // [256][288]  W_a0 (K = 32 stoch + 256 gru)
#define OFF_A1   73728     // [256][256]  W_a1
#define OFF_AMS  139264    // [16][256]   rows 0..5 W_am, 6..11 W_as, 12..15 zero
#define OFF_IMG  143360    // [256][64]   W_img, K padded 38 -> 64 with zeros
#define OFF_IH   159744    // [768][256]  W_ih
#define OFF_HH   356352    // [768][256]  W_hh
#define OFF_P0   552960    // [256][256]  W_p0
#define OFF_PMS  618496    // [64][256]   rows 0..31 W_pm, 32..63 W_ps
#define W_TOTAL  634880

__device__ __forceinline__ short f2b(float v){ __hip_bfloat16 b = __float2bfloat16(v); return __builtin_bit_cast(short, b); }
__device__ __forceinline__ float b2f(short s){ return __bfloat162float(__builtin_bit_cast(__hip_bfloat16, s)); }
__device__ __forceinline__ float sigm(float x){ return 1.f/(1.f + __expf(-x)); }
__device__ __forceinline__ float softp(float x){ return fmaxf(x,0.f) + log1pf(__expf(-fabsf(x))); }
__device__ __forceinline__ float eluf(float x){ return x>0.f ? x : (__expf(x)-1.f); }

__global__ void pack_w(const float* __restrict__ a0, const float* __restrict__ a1,
                       const float* __restrict__ am, const float* __restrict__ as,
                       const float* __restrict__ img, const float* __restrict__ ih,
                       const float* __restrict__ hh, const float* __restrict__ p0,
                       const float* __restrict__ pm, const float* __restrict__ ps,
                       short* __restrict__ ws){
  int i = blockIdx.x*256 + threadIdx.x;
  if (i >= W_TOTAL) return;
  float v;
  if (i < OFF_A1)        v = a0[i];
  else if (i < OFF_AMS)  v = a1[i - OFF_A1];
  else if (i < OFF_IMG){ int j=i-OFF_AMS, r=j>>8, c=j&255; v = r<6 ? am[r*256+c] : (r<12 ? as[(r-6)*256+c] : 0.f); }
  else if (i < OFF_IH){  int j=i-OFF_IMG, r=j>>6, c=j&63;  v = c<38 ? img[r*38+c] : 0.f; }
  else if (i < OFF_HH)   v = ih[i - OFF_IH];
  else if (i < OFF_P0)   v = hh[i - OFF_HH];
  else if (i < OFF_PMS)  v = p0[i - OFF_P0];
  else {                 int j=i-OFF_PMS, r=j>>8, c=j&255; v = r<32 ? pm[r*256+c] : ps[(r-32)*256+c]; }
  ws[i] = f2b(v);
}

// Generic N=256 layer with elu: A[64][K] (LDS) @ W[256][K]^T + bias -> O[64][256] (LDS, stride 264)
__device__ __forceinline__ void dense256(const short* __restrict__ Ab, int astr, int nkb,
                                         const short* __restrict__ W, int wK,
                                         const float* __restrict__ bias,
                                         short* __restrict__ Ob,
                                         int wid, int lrow, int lk){
  #pragma unroll 1
  for (int mt=0; mt<4; ++mt){
    f32x4 acc[4] = {};
    const short* ap = Ab + (mt*16+lrow)*astr + lk*8;
    const int n0 = wid*64 + lrow;
    #pragma unroll
    for (int kb=0; kb<9; ++kb){
      if (kb >= nkb) break;
      short8 a = *(const short8*)(ap + kb*32);
      const short* wp = W + kb*32 + lk*8;
      #pragma unroll
      for (int j=0; j<4; ++j){
        short8 b = *(const short8*)(wp + (n0 + j*16)*wK);
        acc[j] = MFMA_BF16(a, b, acc[j], 0, 0, 0);
      }
    }
    #pragma unroll
    for (int j=0; j<4; ++j){
      int n = n0 + j*16;
      float bs = bias[n];
      #pragma unroll
      for (int i=0; i<4; ++i){
        int row = mt*16 + lk*4 + i;
        Ob[row*264 + n] = f2b(eluf(acc[j][i] + bs));
      }
    }
  }
}

__global__ __launch_bounds__(256) void dream_kernel(
    const float* __restrict__ stoch0, const float* __restrict__ gru0,
    const float* __restrict__ anoise, const float* __restrict__ snoise,
    const short* __restrict__ ws,
    const float* __restrict__ b_a0, const float* __restrict__ b_a1,
    const float* __restrict__ b_am, const float* __restrict__ b_as,
    const float* __restrict__ b_img, const float* __restrict__ b_ih,
    const float* __restrict__ b_hh, const float* __restrict__ b_p0,
    const float* __restrict__ b_pm, const float* __restrict__ b_ps,
    float* __restrict__ out)
{
  __shared__ short bufA[64*264];
  __shared__ short bufB[64*264];
  __shared__ short bufC[64*264];
  __shared__ short simg[64*72];   // [64][72]: cols 0..31 stoch, 32..37 action, 38..63 zero

  const int tid  = threadIdx.x;
  const int wid  = tid >> 6;
  const int lane = tid & 63;
  const int lrow = lane & 15;   // A-row within tile / D-col
  const int lk   = lane >> 4;   // k-group / D-row-group
  const int r0   = blockIdx.x * 64;

  // initial state -> LDS (bf16)
  for (int idx = tid; idx < 64*256; idx += 256){
    int r = idx >> 8, c = idx & 255;
    bufA[r*264 + c] = f2b(gru0[(size_t)(r0+r)*256 + c]);
  }
  for (int idx = tid; idx < 64*32; idx += 256){
    int r = idx >> 5, c = idx & 31;
    simg[r*72 + c]      = f2b(stoch0[(size_t)(r0+r)*32 + c]);
    simg[r*72 + 32 + c] = 0;   // zero action+pad cols 32..63
  }
  __syncthreads();

  short* G = bufA;   // gru state
  short* X = bufB;   // scratch
  short* Y = bufC;   // scratch

  for (int h = 0; h < NH; ++h){
    // ---- a0: elu([stoch|gru] @ W_a0^T + b): K=288 (kb0 from simg, kb1..8 from G) -> X
    #pragma unroll 1
    for (int mt=0; mt<4; ++mt){
      f32x4 acc[4] = {};
      const short* ai = simg + (mt*16+lrow)*72 + lk*8;
      const short* ag = G    + (mt*16+lrow)*264 + lk*8;
      const int n0 = wid*64 + lrow;
      #pragma unroll
      for (int kb=0; kb<9; ++kb){
        short8 a = (kb==0) ? *(const short8*)ai : *(const short8*)(ag + (kb-1)*32);
        const short* wp = ws + OFF_A0 + kb*32 + lk*8;
        #pragma unroll
        for (int j=0; j<4; ++j){
          short8 b = *(const short8*)(wp + (n0 + j*16)*288);
          acc[j] = MFMA_BF16(a, b, acc[j], 0, 0, 0);
        }
      }
      #pragma unroll
      for (int j=0; j<4; ++j){
        int n = n0 + j*16;
        float bs = b_a0[n];
        #pragma unroll
        for (int i=0; i<4; ++i){
          int row = mt*16 + lk*4 + i;
          X[row*264 + n] = f2b(eluf(acc[j][i] + bs));
        }
      }
    }
    __syncthreads();

    // ---- a1: elu(X @ W_a1^T + b) -> Y
    dense256(X, 264, 8, ws + OFF_A1, 256, b_a1, Y, wid, lrow, lk);
    __syncthreads();

    // ---- am/as: Y @ [W_am;W_as]^T, action = mean + softplus(std)*an -> simg cols 32..37
    {
      const int mt = wid;
      f32x4 acc = {};
      const short* ap = Y + (mt*16+lrow)*264 + lk*8;
      const short* wp = ws + OFF_AMS + lrow*256 + lk*8;
      #pragma unroll
      for (int kb=0; kb<8; ++kb){
        short8 a = *(const short8*)(ap + kb*32);
        short8 b = *(const short8*)(wp + kb*32);
        acc = MFMA_BF16(a, b, acc, 0, 0, 0);
      }
      float bs = (lrow<6) ? b_am[lrow] : (lrow<12 ? b_as[lrow-6] : 0.f);
      #pragma unroll
      for (int i=0; i<4; ++i){
        float raw = acc[i] + bs;
        float sp  = softp(raw);
        float spn = __shfl(sp, (lane & 48) | ((lrow + 6) & 15));
        if (lrow < 6){
          int row = mt*16 + lk*4 + i;
          size_t grow = r0 + row;
          float an = anoise[((size_t)h*NB + grow)*NA + lrow];
          simg[row*72 + 32 + lrow] = f2b(raw + spn * an);
        }
      }
    }
    __syncthreads();

    // ---- img: elu([stoch|action|0] @ W_img^T + b): K=64 -> X
    dense256(simg, 72, 2, ws + OFF_IMG, 64, b_img, X, wid, lrow, lk);
    __syncthreads();

    // ---- GRU gates: gi = X@W_ih^T, gh = G@W_hh^T -> new gru in Y + out
    #pragma unroll 1
    for (int mt=0; mt<4; ++mt){
      f32x4 aR[4] = {}, aZ[4] = {}, aN[4] = {}, aH[4] = {};
      const short* xp = X + (mt*16+lrow)*264 + lk*8;
      const short* gp = G + (mt*16+lrow)*264 + lk*8;
      const int c0 = wid*64 + lrow;
      #pragma unroll
      for (int kb=0; kb<8; ++kb){
        short8 a = *(const short8*)(xp + kb*32);
        const short* wp = ws + OFF_IH + kb*32 + lk*8;
        #pragma unroll
        for (int j=0; j<4; ++j){
          int c = c0 + j*16;
          short8 br = *(const short8*)(wp + c*256);
          short8 bz = *(const short8*)(wp + (c+256)*256);
          short8 bn = *(const short8*)(wp + (c+512)*256);
          aR[j] = MFMA_BF16(a, br, aR[j], 0, 0, 0);
          aZ[j] = MFMA_BF16(a, bz, aZ[j], 0, 0, 0);
          aN[j] = MFMA_BF16(a, bn, aN[j], 0, 0, 0);
        }
      }
      #pragma unroll
      for (int kb=0; kb<8; ++kb){
        short8 a = *(const short8*)(gp + kb*32);
        const short* wp = ws + OFF_HH + kb*32 + lk*8;
        #pragma unroll
        for (int j=0; j<4; ++j){
          int c = c0 + j*16;
          short8 br = *(const short8*)(wp + c*256);
          short8 bz = *(const short8*)(wp + (c+256)*256);
          short8 bh = *(const short8*)(wp + (c+512)*256);
          aR[j] = MFMA_BF16(a, br, aR[j], 0, 0, 0);
          aZ[j] = MFMA_BF16(a, bz, aZ[j], 0, 0, 0);
          aH[j] = MFMA_BF16(a, bh, aH[j], 0, 0, 0);
        }
      }
      #pragma unroll
      for (int j=0; j<4; ++j){
        int c = c0 + j*16;
        float bir = b_ih[c]       + b_hh[c];
        float biz = b_ih[256 + c] + b_hh[256 + c];
        float bin = b_ih[512 + c];
        float bhn = b_hh[512 + c];
        #pragma unroll
        for (int i=0; i<4; ++i){
          int row = mt*16 + lk*4 + i;
          float hold = b2f(G[row*264 + c]);
          float r = sigm(aR[j][i] + bir);
          float z = sigm(aZ[j][i] + biz);
          float n = tanhf(aN[j][i] + bin + r*(aH[j][i] + bhn));
          float hnew = (1.f - z)*n + z*hold;
          Y[row*264 + c] = f2b(hnew);
          out[((size_t)h*NB + (size_t)(r0+row))*288 + 32 + c] = hnew;
        }
      }
    }
    __syncthreads();

    // ---- p0: elu(Y @ W_p0^T + b) -> X
    dense256(Y, 264, 8, ws + OFF_P0, 256, b_p0, X, wid, lrow, lk);
    __syncthreads();

    // ---- pm/ps: X @ [W_pm;W_ps]^T, stoch = mean + softplus(std)*sn -> simg cols 0..31 + out
    {
      const int mt = wid;
      f32x4 acc[4] = {};
      const short* ap = X + (mt*16+lrow)*264 + lk*8;
      #pragma unroll
      for (int kb=0; kb<8; ++kb){
        short8 a = *(const short8*)(ap + kb*32);
        const short* wp = ws + OFF_PMS + kb*32 + lk*8;
        #pragma unroll
        for (int j=0; j<4; ++j){
          short8 b = *(const short8*)(wp + (j*16 + lrow)*256);
          acc[j] = MFMA_BF16(a, b, acc[j], 0, 0, 0);
        }
      }
      #pragma unroll
      for (int j=0; j<2; ++j){
        int sc = j*16 + lrow;          // 0..31
        float bm = b_pm[sc], bp = b_ps[sc];
        #pragma unroll
        for (int i=0; i<4; ++i){
          int row = mt*16 + lk*4 + i;
          size_t grow = r0 + row;
          float m  = acc[j][i] + bm;
          float sp = softp(acc[j+2][i] + bp);
          float sn = snoise[((size_t)h*NB + grow)*NS + sc];
          float st = m + sp*sn;
          simg[row*72 + sc] = f2b(st);
          out[((size_t)h*NB + grow)*288 + sc] = st;
        }
      }
    }
    __syncthreads();

    // rotate buffers: newG = Y, scratch = {old G, old X}
    short* t = G; G = Y; Y = X; X = t;
  }
}

extern "C" void kernel_launch(void* const* d_in, const int* in_sizes, int n_in,
                              void* d_out, int out_size, void* d_ws, size_t ws_size,
                              hipStream_t stream){
  const float* stoch0 = (const float*)d_in[0];
  const float* gru0   = (const float*)d_in[1];
  const float* anoise = (const float*)d_in[2];
  const float* snoise = (const float*)d_in[3];
  const float* Wa0 = (const float*)d_in[4];   const float* ba0 = (const float*)d_in[5];
  const float* Wa1 = (const float*)d_in[6];   const float* ba1 = (const float*)d_in[7];
  const float* Wam = (const float*)d_in[8];   const float* bam = (const float*)d_in[9];
  const float* Was = (const float*)d_in[10];  const float* bas = (const float*)d_in[11];
  const float* Wimg= (const float*)d_in[12];  const float* bimg= (const float*)d_in[13];
  const float* Wih = (const float*)d_in[14];  const float* bih = (const float*)d_in[15];
  const float* Whh = (const float*)d_in[16];  const float* bhh = (const float*)d_in[17];
  const float* Wp0 = (const float*)d_in[18];  const float* bp0 = (const float*)d_in[19];
  const float* Wpm = (const float*)d_in[20];  const float* bpm = (const float*)d_in[21];
  const float* Wps = (const float*)d_in[22];  const float* bps = (const float*)d_in[23];
  short* ws  = (short*)d_ws;
  float* out = (float*)d_out;

  pack_w<<<(W_TOTAL + 255)/256, 256, 0, stream>>>(Wa0, Wa1, Wam, Was, Wimg, Wih, Whh, Wp0, Wpm, Wps, ws);
  dream_kernel<<<NB/64, 256, 0, stream>>>(stoch0, gru0, anoise, snoise, ws,
                                          ba0, ba1, bam, bas, bimg, bih, bhh, bp0, bpm, bps, out);
}

// Round 4
// 4184.218 us; speedup vs baseline: 1.0191x; 1.0191x over previous
//
#include <hip/hip_runtime.h>
#include <hip/hip_bf16.h>

#define MFMA_BF16 __builtin_amdgcn_mfma_f32_16x16x32_bf16

typedef __attribute__((ext_vector_type(8))) short short8;
typedef __attribute__((ext_vector_type(4))) float f32x4;

#define NB 16384
#define NH 15
#define NS 32
#define ND 256
#define NHID 256
#define NA 6

// bf16 weight workspace layout (element offsets)
#define OFF_A0   0         // [256][288]  W_a0 (K = 32 stoch + 256 gru)
#define OFF_A1   73728     // [256][256]  W_a1
#define OFF_AMS  139264    // [16][256]   rows 0..5 W_am, 6..11 W_as, 12..15 zero
#define OFF_IMG  143360    // [256][64]   W_img, K padded 38 -> 64 with zeros
#define OFF_IH   159744    // [768][256]  W_ih
#define OFF_HH   356352    // [768][256]  W_hh
#define OFF_P0   552960    // [256][256]  W_p0
#define OFF_PMS  618496    // [64][256]   rows 0..31 W_pm, 32..63 W_ps
#define W_TOTAL  634880

__device__ __forceinline__ short f2b(float v){ __hip_bfloat16 b = __float2bfloat16(v); return __builtin_bit_cast(short, b); }
__device__ __forceinline__ float b2f(short s){ return __bfloat162float(__builtin_bit_cast(__hip_bfloat16, s)); }
__device__ __forceinline__ float sigm(float x){ return 1.f/(1.f + __expf(-x)); }
__device__ __forceinline__ float softp(float x){ return fmaxf(x,0.f) + log1pf(__expf(-fabsf(x))); }
__device__ __forceinline__ float eluf(float x){ return x>0.f ? x : (__expf(x)-1.f); }

__global__ void pack_w(const float* __restrict__ a0, const float* __restrict__ a1,
                       const float* __restrict__ am, const float* __restrict__ as,
                       const float* __restrict__ img, const float* __restrict__ ih,
                       const float* __restrict__ hh, const float* __restrict__ p0,
                       const float* __restrict__ pm, const float* __restrict__ ps,
                       short* __restrict__ ws){
  int i = blockIdx.x*256 + threadIdx.x;
  if (i >= W_TOTAL) return;
  float v;
  if (i < OFF_A1)        v = a0[i];
  else if (i < OFF_AMS)  v = a1[i - OFF_A1];
  else if (i < OFF_IMG){ int j=i-OFF_AMS, r=j>>8, c=j&255; v = r<6 ? am[r*256+c] : (r<12 ? as[(r-6)*256+c] : 0.f); }
  else if (i < OFF_IH){  int j=i-OFF_IMG, r=j>>6, c=j&63;  v = c<38 ? img[r*38+c] : 0.f; }
  else if (i < OFF_HH)   v = ih[i - OFF_IH];
  else if (i < OFF_P0)   v = hh[i - OFF_HH];
  else if (i < OFF_PMS)  v = p0[i - OFF_P0];
  else {                 int j=i-OFF_PMS, r=j>>8, c=j&255; v = r<32 ? pm[r*256+c] : ps[(r-32)*256+c]; }
  ws[i] = f2b(v);
}

// N=256 layer: A[64][K](LDS) @ W[256][K]^T + bias (+elu) -> O[64][256] (LDS stride 264)
// kb-outermost: weights read ONCE per wave; acc[2 mtiles][4 colgroups].
// n0 MUST be lane-dependent: (wid&3)*64 + lrow.
template<int NKB, int WK, bool ELU>
__device__ __forceinline__ void dense_n256(const short* __restrict__ Ab, int astr,
                                           const short* __restrict__ W,
                                           const float* __restrict__ bias,
                                           short* __restrict__ Ob,
                                           int mbase, int n0, int lrow, int lk){
  f32x4 acc[2][4] = {};
  const short* ap = Ab + (mbase + lrow)*astr + lk*8;
  const int astep = 16*astr;
  #pragma unroll
  for (int kb=0; kb<NKB; ++kb){
    short8 a0 = *(const short8*)(ap + kb*32);
    short8 a1 = *(const short8*)(ap + astep + kb*32);
    const short* wp = W + kb*32 + lk*8;
    #pragma unroll
    for (int j=0; j<4; ++j){
      short8 b = *(const short8*)(wp + (size_t)(n0 + j*16)*WK);
      acc[0][j] = MFMA_BF16(a0, b, acc[0][j], 0, 0, 0);
      acc[1][j] = MFMA_BF16(a1, b, acc[1][j], 0, 0, 0);
    }
  }
  #pragma unroll
  for (int mt=0; mt<2; ++mt){
    #pragma unroll
    for (int j=0; j<4; ++j){
      int n = n0 + j*16;
      float bs = bias[n];
      #pragma unroll
      for (int i=0; i<4; ++i){
        int row = mbase + mt*16 + lk*4 + i;
        float v = acc[mt][j][i] + bs;
        Ob[row*264 + n] = f2b(ELU ? eluf(v) : v);
      }
    }
  }
}

__global__ __launch_bounds__(512) void dream_kernel(
    const float* __restrict__ stoch0, const float* __restrict__ gru0,
    const float* __restrict__ anoise, const float* __restrict__ snoise,
    const short* __restrict__ ws,
    const float* __restrict__ b_a0, const float* __restrict__ b_a1,
    const float* __restrict__ b_am, const float* __restrict__ b_as,
    const float* __restrict__ b_img, const float* __restrict__ b_ih,
    const float* __restrict__ b_hh, const float* __restrict__ b_p0,
    const float* __restrict__ b_pm, const float* __restrict__ b_ps,
    float* __restrict__ out)
{
  __shared__ short bufA[64*264];
  __shared__ short bufB[64*264];
  __shared__ short bufC[64*264];
  __shared__ short simg[64*72];   // [64][72]: cols 0..31 stoch, 32..37 action, 38..63 zero

  const int tid   = threadIdx.x;
  const int wid   = tid >> 6;       // 0..7
  const int lane  = tid & 63;
  const int lrow  = lane & 15;
  const int lk    = lane >> 4;
  const int mbase = (wid >> 2) * 32;        // M-tile pair base (0 or 32)
  const int n0    = (wid & 3) * 64 + lrow;  // column base — lane-dependent!
  const int r0    = blockIdx.x * 64;

  // initial state -> LDS (bf16)
  for (int idx = tid; idx < 64*256; idx += 512){
    int r = idx >> 8, c = idx & 255;
    bufA[r*264 + c] = f2b(gru0[(size_t)(r0+r)*256 + c]);
  }
  for (int idx = tid; idx < 64*32; idx += 512){
    int r = idx >> 5, c = idx & 31;
    simg[r*72 + c]      = f2b(stoch0[(size_t)(r0+r)*32 + c]);
    simg[r*72 + 32 + c] = 0;   // zero action+pad cols 32..63
  }
  __syncthreads();

  short* G = bufA;   // gru state
  short* X = bufB;   // scratch
  short* Y = bufC;   // scratch

  for (int h = 0; h < NH; ++h){
    // ---- a0: elu([stoch|gru] @ W_a0^T + b): K=288 (kb0 simg, kb1..8 G) -> X
    {
      f32x4 acc[2][4] = {};
      const short* ai = simg + (mbase+lrow)*72  + lk*8;
      const short* ag = G    + (mbase+lrow)*264 + lk*8;
      #pragma unroll
      for (int kb=0; kb<9; ++kb){
        short8 a0 = (kb==0) ? *(const short8*)ai : *(const short8*)(ag + (kb-1)*32);
        short8 a1 = (kb==0) ? *(const short8*)(ai + 16*72) : *(const short8*)(ag + 16*264 + (kb-1)*32);
        const short* wp = ws + OFF_A0 + kb*32 + lk*8;
        #pragma unroll
        for (int j=0; j<4; ++j){
          short8 b = *(const short8*)(wp + (size_t)(n0 + j*16)*288);
          acc[0][j] = MFMA_BF16(a0, b, acc[0][j], 0, 0, 0);
          acc[1][j] = MFMA_BF16(a1, b, acc[1][j], 0, 0, 0);
        }
      }
      #pragma unroll
      for (int mt=0; mt<2; ++mt)
        #pragma unroll
        for (int j=0; j<4; ++j){
          int n = n0 + j*16;
          float bs = b_a0[n];
          #pragma unroll
          for (int i=0; i<4; ++i){
            int row = mbase + mt*16 + lk*4 + i;
            X[row*264 + n] = f2b(eluf(acc[mt][j][i] + bs));
          }
        }
    }
    __syncthreads();

    // ---- a1: elu(X @ W_a1^T + b) -> Y
    dense_n256<8,256,true>(X, 264, ws + OFF_A1, b_a1, Y, mbase, n0, lrow, lk);
    __syncthreads();

    // ---- am/as: Y @ [W_am;W_as]^T, action = mean + softplus(std)*an -> simg cols 32..37
    if (wid < 4){
      const int mt = wid;
      f32x4 acc = {};
      const short* ap = Y + (mt*16+lrow)*264 + lk*8;
      const short* wp = ws + OFF_AMS + lrow*256 + lk*8;
      #pragma unroll
      for (int kb=0; kb<8; ++kb){
        short8 a = *(const short8*)(ap + kb*32);
        short8 b = *(const short8*)(wp + kb*32);
        acc = MFMA_BF16(a, b, acc, 0, 0, 0);
      }
      float bs = (lrow<6) ? b_am[lrow] : (lrow<12 ? b_as[lrow-6] : 0.f);
      #pragma unroll
      for (int i=0; i<4; ++i){
        float raw = acc[i] + bs;
        float sp  = softp(raw);
        float spn = __shfl(sp, (lane & 48) | ((lrow + 6) & 15));
        if (lrow < 6){
          int row = mt*16 + lk*4 + i;
          size_t grow = r0 + row;
          float an = __builtin_nontemporal_load(&anoise[((size_t)h*NB + grow)*NA + lrow]);
          simg[row*72 + 32 + lrow] = f2b(raw + spn * an);
        }
      }
    }
    __syncthreads();

    // ---- img: elu([stoch|action|0] @ W_img^T + b): K=64 -> X
    dense_n256<2,64,true>(simg, 72, ws + OFF_IMG, b_img, X, mbase, n0, lrow, lk);
    __syncthreads();

    // ---- GRU: fused K=512 pass, gates in registers -> Y + out
    #pragma unroll 1
    for (int mt=0; mt<2; ++mt){
      f32x4 aR[4] = {}, aZ[4] = {}, aI[4] = {}, aH[4] = {};
      const int rbase = mbase + mt*16;
      const short* xp = X + (rbase+lrow)*264 + lk*8;
      const short* gp = G + (rbase+lrow)*264 + lk*8;
      #pragma unroll
      for (int kb=0; kb<8; ++kb){
        short8 a = *(const short8*)(xp + kb*32);
        const short* wp = ws + OFF_IH + kb*32 + lk*8;
        #pragma unroll
        for (int j=0; j<4; ++j){
          int c = n0 + j*16;
          short8 br = *(const short8*)(wp + (size_t)c*256);
          short8 bz = *(const short8*)(wp + (size_t)(c+256)*256);
          short8 bn = *(const short8*)(wp + (size_t)(c+512)*256);
          aR[j] = MFMA_BF16(a, br, aR[j], 0, 0, 0);
          aZ[j] = MFMA_BF16(a, bz, aZ[j], 0, 0, 0);
          aI[j] = MFMA_BF16(a, bn, aI[j], 0, 0, 0);
        }
      }
      #pragma unroll
      for (int kb=0; kb<8; ++kb){
        short8 a = *(const short8*)(gp + kb*32);
        const short* wp = ws + OFF_HH + kb*32 + lk*8;
        #pragma unroll
        for (int j=0; j<4; ++j){
          int c = n0 + j*16;
          short8 br = *(const short8*)(wp + (size_t)c*256);
          short8 bz = *(const short8*)(wp + (size_t)(c+256)*256);
          short8 bh = *(const short8*)(wp + (size_t)(c+512)*256);
          aR[j] = MFMA_BF16(a, br, aR[j], 0, 0, 0);
          aZ[j] = MFMA_BF16(a, bz, aZ[j], 0, 0, 0);
          aH[j] = MFMA_BF16(a, bh, aH[j], 0, 0, 0);
        }
      }
      #pragma unroll
      for (int j=0; j<4; ++j){
        int c = n0 + j*16;
        float bir = b_ih[c]       + b_hh[c];
        float biz = b_ih[256 + c] + b_hh[256 + c];
        float bin = b_ih[512 + c];
        float bhn = b_hh[512 + c];
        #pragma unroll
        for (int i=0; i<4; ++i){
          int row = rbase + lk*4 + i;
          float hold = b2f(G[row*264 + c]);
          float r = sigm(aR[j][i] + bir);
          float z = sigm(aZ[j][i] + biz);
          float n = tanhf(aI[j][i] + bin + r*(aH[j][i] + bhn));
          float hnew = (1.f - z)*n + z*hold;
          Y[row*264 + c] = f2b(hnew);
          __builtin_nontemporal_store(hnew, &out[((size_t)h*NB + (size_t)(r0+row))*288 + 32 + c]);
        }
      }
    }
    __syncthreads();

    // ---- p0: elu(Y @ W_p0^T + b) -> X
    dense_n256<8,256,true>(Y, 264, ws + OFF_P0, b_p0, X, mbase, n0, lrow, lk);
    __syncthreads();

    // ---- pm/ps: X @ [W_pm;W_ps]^T, stoch = mean + softplus(std)*sn -> simg cols 0..31 + out
    if (wid < 4){
      const int mt = wid;
      f32x4 acc[4] = {};
      const short* ap = X + (mt*16+lrow)*264 + lk*8;
      #pragma unroll
      for (int kb=0; kb<8; ++kb){
        short8 a = *(const short8*)(ap + kb*32);
        const short* wp = ws + OFF_PMS + kb*32 + lk*8;
        #pragma unroll
        for (int j=0; j<4; ++j){
          short8 b = *(const short8*)(wp + (size_t)(j*16 + lrow)*256);
          acc[j] = MFMA_BF16(a, b, acc[j], 0, 0, 0);
        }
      }
      #pragma unroll
      for (int j=0; j<2; ++j){
        int sc = j*16 + lrow;          // 0..31
        float bm = b_pm[sc], bp = b_ps[sc];
        #pragma unroll
        for (int i=0; i<4; ++i){
          int row = mt*16 + lk*4 + i;
          size_t grow = r0 + row;
          float m  = acc[j][i] + bm;
          float sp = softp(acc[j+2][i] + bp);
          float sn = __builtin_nontemporal_load(&snoise[((size_t)h*NB + grow)*NS + sc]);
          float st = m + sp*sn;
          simg[row*72 + sc] = f2b(st);
          __builtin_nontemporal_store(st, &out[((size_t)h*NB + grow)*288 + sc]);
        }
      }
    }
    __syncthreads();

    // rotate buffers: newG = Y, scratch = {old G, old X}
    short* t = G; G = Y; Y = X; X = t;
  }
}

extern "C" void kernel_launch(void* const* d_in, const int* in_sizes, int n_in,
                              void* d_out, int out_size, void* d_ws, size_t ws_size,
                              hipStream_t stream){
  const float* stoch0 = (const float*)d_in[0];
  const float* gru0   = (const float*)d_in[1];
  const float* anoise = (const float*)d_in[2];
  const float* snoise = (const float*)d_in[3];
  const float* Wa0 = (const float*)d_in[4];   const float* ba0 = (const float*)d_in[5];
  const float* Wa1 = (const float*)d_in[6];   const float* ba1 = (const float*)d_in[7];
  const float* Wam = (const float*)d_in[8];   const float* bam = (const float*)d_in[9];
  const float* Was = (const float*)d_in[10];  const float* bas = (const float*)d_in[11];
  const float* Wimg= (const float*)d_in[12];  const float* bimg= (const float*)d_in[13];
  const float* Wih = (const float*)d_in[14];  const float* bih = (const float*)d_in[15];
  const float* Whh = (const float*)d_in[16];  const float* bhh = (const float*)d_in[17];
  const float* Wp0 = (const float*)d_in[18];  const float* bp0 = (const float*)d_in[19];
  const float* Wpm = (const float*)d_in[20];  const float* bpm = (const float*)d_in[21];
  const float* Wps = (const float*)d_in[22];  const float* bps = (const float*)d_in[23];
  short* ws  = (short*)d_ws;
  float* out = (float*)d_out;

  pack_w<<<(W_TOTAL + 255)/256, 256, 0, stream>>>(Wa0, Wa1, Wam, Was, Wimg, Wih, Whh, Wp0, Wpm, Wps, ws);
  dream_kernel<<<NB/64, 512, 0, stream>>>(stoch0, gru0, anoise, snoise, ws,
                                          ba0, ba1, bam, bas, bimg, bih, bhh, bp0, bpm, bps, out);
}

// Round 5
// 1508.618 us; speedup vs baseline: 2.8266x; 2.7735x over previous
//
#include <hip/hip_runtime.h>
#include <hip/hip_bf16.h>

#define MFMA_BF16 __builtin_amdgcn_mfma_f32_16x16x32_bf16

typedef __attribute__((ext_vector_type(8))) short short8;
typedef __attribute__((ext_vector_type(4))) float f32x4;

#define NB 16384
#define NH 15
#define NS 32
#define ND 256
#define NHID 256
#define NA 6

// bf16 weight workspace, B-frag tiled layout:
// matrix [N][K] -> tiles t=n/16, kb=k/32; tile = 512 shorts (1KB) in lane order:
//   elem(lane, e) = W[t*16 + (lane&15)][kb*32 + (lane>>4)*8 + e]
// tile offset = OFF + (t*KB + kb)*512,  KB = K/32
#define OFF_A0   0         // N=256 K=288 (32 stoch | 256 gru), KB=9, 16 tiles
#define OFF_A1   73728     // N=256 K=256, KB=8
#define OFF_AMS  139264    // N=16  K=256: rows 0..5 W_am, 6..11 W_as, 12..15 zero
#define OFF_IMG  143360    // N=256 K=64 (38 padded), KB=2
#define OFF_IH   159744    // N=768 K=256, KB=8, 48 tiles
#define OFF_HH   356352    // N=768 K=256
#define OFF_P0   552960    // N=256 K=256
#define OFF_PMS  618496    // N=64  K=256: rows 0..31 W_pm, 32..63 W_ps
#define W_TOTAL  634880

__device__ __forceinline__ short f2b(float v){ __hip_bfloat16 b = __float2bfloat16(v); return __builtin_bit_cast(short, b); }
__device__ __forceinline__ float b2f(short s){ return __bfloat162float(__builtin_bit_cast(__hip_bfloat16, s)); }
__device__ __forceinline__ float sigm(float x){ return 1.f/(1.f + __expf(-x)); }
__device__ __forceinline__ float softp(float x){ return fmaxf(x,0.f) + log1pf(__expf(-fabsf(x))); }
__device__ __forceinline__ float eluf(float x){ return x>0.f ? x : (__expf(x)-1.f); }

__device__ __forceinline__ void decode_frag(int m, int KB, int& row, int& k){
  int tidx = m >> 9, w = m & 511;
  int lane = w >> 3, e = w & 7;
  int t = tidx / KB, kb = tidx - t*KB;
  row = t*16 + (lane & 15);
  k   = kb*32 + ((lane >> 4) << 3) + e;
}

__global__ void pack_w(const float* __restrict__ a0, const float* __restrict__ a1,
                       const float* __restrict__ am, const float* __restrict__ as,
                       const float* __restrict__ img, const float* __restrict__ ih,
                       const float* __restrict__ hh, const float* __restrict__ p0,
                       const float* __restrict__ pm, const float* __restrict__ ps,
                       short* __restrict__ ws){
  int i = blockIdx.x*256 + threadIdx.x;
  if (i >= W_TOTAL) return;
  int row, k; float v;
  if (i < OFF_A1){        decode_frag(i - OFF_A0, 9, row, k);  v = a0[row*288 + k]; }
  else if (i < OFF_AMS){  decode_frag(i - OFF_A1, 8, row, k);  v = a1[row*256 + k]; }
  else if (i < OFF_IMG){  decode_frag(i - OFF_AMS, 8, row, k);
                          v = row<6 ? am[row*256+k] : (row<12 ? as[(row-6)*256+k] : 0.f); }
  else if (i < OFF_IH){   decode_frag(i - OFF_IMG, 2, row, k);
                          v = k<38 ? img[row*38 + k] : 0.f; }
  else if (i < OFF_HH){   decode_frag(i - OFF_IH, 8, row, k);  v = ih[row*256 + k]; }
  else if (i < OFF_P0){   decode_frag(i - OFF_HH, 8, row, k);  v = hh[row*256 + k]; }
  else if (i < OFF_PMS){  decode_frag(i - OFF_P0, 8, row, k);  v = p0[row*256 + k]; }
  else {                  decode_frag(i - OFF_PMS, 8, row, k);
                          v = row<32 ? pm[row*256+k] : ps[(row-32)*256+k]; }
  ws[i] = f2b(v);
}

// N=256 layer: A[64][K](LDS) @ W^T + bias (+elu) -> O[64][256] (LDS stride 264)
// B loads coalesced: tile (tbase+j, kb) at +lane*8.
template<int KB, bool ELU>
__device__ __forceinline__ void dense_n256(const short* __restrict__ Ab, int astr,
                                           const short* __restrict__ W,
                                           const float* __restrict__ bias,
                                           short* __restrict__ Ob,
                                           int mbase, int tbase, int n0, int lane, int lk){
  f32x4 acc[2][4] = {};
  const short* ap = Ab + (mbase + (lane & 15))*astr + lk*8;
  const int astep = 16*astr;
  const short* wl = W + lane*8;
  #pragma unroll
  for (int kb=0; kb<KB; ++kb){
    short8 a0 = *(const short8*)(ap + kb*32);
    short8 a1 = *(const short8*)(ap + astep + kb*32);
    #pragma unroll
    for (int j=0; j<4; ++j){
      short8 b = *(const short8*)(wl + ((tbase + j)*KB + kb)*512);
      acc[0][j] = MFMA_BF16(a0, b, acc[0][j], 0, 0, 0);
      acc[1][j] = MFMA_BF16(a1, b, acc[1][j], 0, 0, 0);
    }
  }
  #pragma unroll
  for (int mt=0; mt<2; ++mt){
    #pragma unroll
    for (int j=0; j<4; ++j){
      int n = n0 + j*16;
      float bs = bias[n];
      #pragma unroll
      for (int i=0; i<4; ++i){
        int row = mbase + mt*16 + lk*4 + i;
        float v = acc[mt][j][i] + bs;
        Ob[row*264 + n] = f2b(ELU ? eluf(v) : v);
      }
    }
  }
}

__global__ __launch_bounds__(512) void dream_kernel(
    const float* __restrict__ stoch0, const float* __restrict__ gru0,
    const float* __restrict__ anoise, const float* __restrict__ snoise,
    const short* __restrict__ ws,
    const float* __restrict__ b_a0, const float* __restrict__ b_a1,
    const float* __restrict__ b_am, const float* __restrict__ b_as,
    const float* __restrict__ b_img, const float* __restrict__ b_ih,
    const float* __restrict__ b_hh, const float* __restrict__ b_p0,
    const float* __restrict__ b_pm, const float* __restrict__ b_ps,
    float* __restrict__ out)
{
  __shared__ short bufA[64*264];
  __shared__ short bufB[64*264];
  __shared__ short bufC[64*264];
  __shared__ short simg[64*72];   // [64][72]: cols 0..31 stoch, 32..37 action, 38..63 zero

  const int tid   = threadIdx.x;
  const int wid   = tid >> 6;       // 0..7
  const int lane  = tid & 63;
  const int lrow  = lane & 15;
  const int lk    = lane >> 4;
  const int mbase = (wid >> 2) * 32;        // M-tile pair base (0 or 32)
  const int tbase = (wid & 3) * 4;          // B n-tile base
  const int n0    = (wid & 3) * 64 + lrow;  // output column base (lane-dependent)
  const int r0    = blockIdx.x * 64;

  // initial state -> LDS (bf16)
  for (int idx = tid; idx < 64*256; idx += 512){
    int r = idx >> 8, c = idx & 255;
    bufA[r*264 + c] = f2b(gru0[(size_t)(r0+r)*256 + c]);
  }
  for (int idx = tid; idx < 64*32; idx += 512){
    int r = idx >> 5, c = idx & 31;
    simg[r*72 + c]      = f2b(stoch0[(size_t)(r0+r)*32 + c]);
    simg[r*72 + 32 + c] = 0;   // zero action+pad cols 32..63
  }
  __syncthreads();

  short* G = bufA;   // gru state
  short* X = bufB;   // scratch
  short* Y = bufC;   // scratch

  for (int h = 0; h < NH; ++h){
    // ---- a0: elu([stoch|gru] @ W_a0^T + b): K=288 (kb0 simg, kb1..8 G) -> X
    {
      f32x4 acc[2][4] = {};
      const short* ai = simg + (mbase+lrow)*72  + lk*8;
      const short* ag = G    + (mbase+lrow)*264 + lk*8;
      const short* wl = ws + OFF_A0 + lane*8;
      #pragma unroll
      for (int kb=0; kb<9; ++kb){
        short8 a0 = (kb==0) ? *(const short8*)ai : *(const short8*)(ag + (kb-1)*32);
        short8 a1 = (kb==0) ? *(const short8*)(ai + 16*72) : *(const short8*)(ag + 16*264 + (kb-1)*32);
        #pragma unroll
        for (int j=0; j<4; ++j){
          short8 b = *(const short8*)(wl + ((tbase + j)*9 + kb)*512);
          acc[0][j] = MFMA_BF16(a0, b, acc[0][j], 0, 0, 0);
          acc[1][j] = MFMA_BF16(a1, b, acc[1][j], 0, 0, 0);
        }
      }
      #pragma unroll
      for (int mt=0; mt<2; ++mt)
        #pragma unroll
        for (int j=0; j<4; ++j){
          int n = n0 + j*16;
          float bs = b_a0[n];
          #pragma unroll
          for (int i=0; i<4; ++i){
            int row = mbase + mt*16 + lk*4 + i;
            X[row*264 + n] = f2b(eluf(acc[mt][j][i] + bs));
          }
        }
    }
    __syncthreads();

    // ---- a1: elu(X @ W_a1^T + b) -> Y
    dense_n256<8,true>(X, 264, ws + OFF_A1, b_a1, Y, mbase, tbase, n0, lane, lk);
    __syncthreads();

    // ---- am/as: Y @ [W_am;W_as]^T, action = mean + softplus(std)*an -> simg cols 32..37
    if (wid < 4){
      const int mt = wid;
      f32x4 acc = {};
      const short* ap = Y + (mt*16+lrow)*264 + lk*8;
      const short* wl = ws + OFF_AMS + lane*8;
      #pragma unroll
      for (int kb=0; kb<8; ++kb){
        short8 a = *(const short8*)(ap + kb*32);
        short8 b = *(const short8*)(wl + kb*512);
        acc = MFMA_BF16(a, b, acc, 0, 0, 0);
      }
      float bs = (lrow<6) ? b_am[lrow] : (lrow<12 ? b_as[lrow-6] : 0.f);
      #pragma unroll
      for (int i=0; i<4; ++i){
        float raw = acc[i] + bs;
        float sp  = softp(raw);
        float spn = __shfl(sp, (lane & 48) | ((lrow + 6) & 15));
        if (lrow < 6){
          int row = mt*16 + lk*4 + i;
          size_t grow = r0 + row;
          float an = __builtin_nontemporal_load(&anoise[((size_t)h*NB + grow)*NA + lrow]);
          simg[row*72 + 32 + lrow] = f2b(raw + spn * an);
        }
      }
    }
    __syncthreads();

    // ---- img: elu([stoch|action|0] @ W_img^T + b): K=64 -> X
    dense_n256<2,true>(simg, 72, ws + OFF_IMG, b_img, X, mbase, tbase, n0, lane, lk);
    __syncthreads();

    // ---- GRU: j-outer, weights loaded once; gates in registers -> Y + out
    #pragma unroll 1
    for (int j=0; j<4; ++j){
      f32x4 aR[2] = {}, aZ[2] = {}, aI[2] = {}, aH[2] = {};
      const short* xp = X + (mbase+lrow)*264 + lk*8;
      const short* gp = G + (mbase+lrow)*264 + lk*8;
      const int tr = tbase + j;
      const short* wl_ih = ws + OFF_IH + lane*8;
      const short* wl_hh = ws + OFF_HH + lane*8;
      #pragma unroll
      for (int kb=0; kb<8; ++kb){
        short8 br = *(const short8*)(wl_ih + ((tr     )*8 + kb)*512);
        short8 bz = *(const short8*)(wl_ih + ((tr + 16)*8 + kb)*512);
        short8 bn = *(const short8*)(wl_ih + ((tr + 32)*8 + kb)*512);
        short8 cr = *(const short8*)(wl_hh + ((tr     )*8 + kb)*512);
        short8 cz = *(const short8*)(wl_hh + ((tr + 16)*8 + kb)*512);
        short8 ch = *(const short8*)(wl_hh + ((tr + 32)*8 + kb)*512);
        #pragma unroll
        for (int mt=0; mt<2; ++mt){
          short8 ax = *(const short8*)(xp + mt*16*264 + kb*32);
          short8 ag = *(const short8*)(gp + mt*16*264 + kb*32);
          aR[mt] = MFMA_BF16(ax, br, aR[mt], 0, 0, 0);
          aZ[mt] = MFMA_BF16(ax, bz, aZ[mt], 0, 0, 0);
          aI[mt] = MFMA_BF16(ax, bn, aI[mt], 0, 0, 0);
          aR[mt] = MFMA_BF16(ag, cr, aR[mt], 0, 0, 0);
          aZ[mt] = MFMA_BF16(ag, cz, aZ[mt], 0, 0, 0);
          aH[mt] = MFMA_BF16(ag, ch, aH[mt], 0, 0, 0);
        }
      }
      int c = n0 + j*16;
      float bir = b_ih[c]       + b_hh[c];
      float biz = b_ih[256 + c] + b_hh[256 + c];
      float bin = b_ih[512 + c];
      float bhn = b_hh[512 + c];
      #pragma unroll
      for (int mt=0; mt<2; ++mt){
        #pragma unroll
        for (int i=0; i<4; ++i){
          int row = mbase + mt*16 + lk*4 + i;
          float hold = b2f(G[row*264 + c]);
          float r = sigm(aR[mt][i] + bir);
          float z = sigm(aZ[mt][i] + biz);
          float n = tanhf(aI[mt][i] + bin + r*(aH[mt][i] + bhn));
          float hnew = (1.f - z)*n + z*hold;
          Y[row*264 + c] = f2b(hnew);
          __builtin_nontemporal_store(hnew, &out[((size_t)h*NB + (size_t)(r0+row))*288 + 32 + c]);
        }
      }
    }
    __syncthreads();

    // ---- p0: elu(Y @ W_p0^T + b) -> X
    dense_n256<8,true>(Y, 264, ws + OFF_P0, b_p0, X, mbase, tbase, n0, lane, lk);
    __syncthreads();

    // ---- pm/ps: X @ [W_pm;W_ps]^T, stoch = mean + softplus(std)*sn -> simg cols 0..31 + out
    if (wid < 4){
      const int mt = wid;
      f32x4 acc[4] = {};
      const short* ap = X + (mt*16+lrow)*264 + lk*8;
      const short* wl = ws + OFF_PMS + lane*8;
      #pragma unroll
      for (int kb=0; kb<8; ++kb){
        short8 a = *(const short8*)(ap + kb*32);
        #pragma unroll
        for (int j=0; j<4; ++j){
          short8 b = *(const short8*)(wl + (j*8 + kb)*512);
          acc[j] = MFMA_BF16(a, b, acc[j], 0, 0, 0);
        }
      }
      #pragma unroll
      for (int j=0; j<2; ++j){
        int sc = j*16 + lrow;          // 0..31
        float bm = b_pm[sc], bp = b_ps[sc];
        #pragma unroll
        for (int i=0; i<4; ++i){
          int row = mt*16 + lk*4 + i;
          size_t grow = r0 + row;
          float m  = acc[j][i] + bm;
          float sp = softp(acc[j+2][i] + bp);
          float sn = __builtin_nontemporal_load(&snoise[((size_t)h*NB + grow)*NS + sc]);
          float st = m + sp*sn;
          simg[row*72 + sc] = f2b(st);
          __builtin_nontemporal_store(st, &out[((size_t)h*NB + grow)*288 + sc]);
        }
      }
    }
    __syncthreads();

    // rotate buffers: newG = Y, scratch = {old G, old X}
    short* t = G; G = Y; Y = X; X = t;
  }
}

extern "C" void kernel_launch(void* const* d_in, const int* in_sizes, int n_in,
                              void* d_out, int out_size, void* d_ws, size_t ws_size,
                              hipStream_t stream){
  const float* stoch0 = (const float*)d_in[0];
  const float* gru0   = (const float*)d_in[1];
  const float* anoise = (const float*)d_in[2];
  const float* snoise = (const float*)d_in[3];
  const float* Wa0 = (const float*)d_in[4];   const float* ba0 = (const float*)d_in[5];
  const float* Wa1 = (const float*)d_in[6];   const float* ba1 = (const float*)d_in[7];
  const float* Wam = (const float*)d_in[8];   const float* bam = (const float*)d_in[9];
  const float* Was = (const float*)d_in[10];  const float* bas = (const float*)d_in[11];
  const float* Wimg= (const float*)d_in[12];  const float* bimg= (const float*)d_in[13];
  const float* Wih = (const float*)d_in[14];  const float* bih = (const float*)d_in[15];
  const float* Whh = (const float*)d_in[16];  const float* bhh = (const float*)d_in[17];
  const float* Wp0 = (const float*)d_in[18];  const float* bp0 = (const float*)d_in[19];
  const float* Wpm = (const float*)d_in[20];  const float* bpm = (const float*)d_in[21];
  const float* Wps = (const float*)d_in[22];  const float* bps = (const float*)d_in[23];
  short* ws  = (short*)d_ws;
  float* out = (float*)d_out;

  pack_w<<<(W_TOTAL + 255)/256, 256, 0, stream>>>(Wa0, Wa1, Wam, Was, Wimg, Wih, Whh, Wp0, Wpm, Wps, ws);
  dream_kernel<<<NB/64, 512, 0, stream>>>(stoch0, gru0, anoise, snoise, ws,
                                          ba0, ba1, bam, bas, bimg, bih, bhh, bp0, bpm, bps, out);
}